// Round 3
// baseline (90.162 us; speedup 1.0000x reference)
//
#include <hip/hip_runtime.h>
#include <hip/hip_bf16.h>

#define NROWS 32768
#define NE    1024
#define ED    64
#define RPB   32   // rows per block
#define RPW   8    // rows per wave
#define CHUNK 256  // codes staged per LDS chunk

typedef float4 f4;

// ---------------------------------------------------------------------------
// Outputs are FLOAT32 (reference dtypes: f32 z_q_st, int32 idx, f32 loss):
//   out[0 .. 2097152)          z_q_st (f32)
//   out[2097152 .. 2129920)    idx as float (f32)
//   out[2129920]               loss (f32)
// Per block: 32 z-rows. Codebook processed in 4 chunks of 256 codes, each
// chunk transposed into LDS ([64][256]) with per-code ssq (numpy pairwise-8).
// Distances replicate np f32 op order: fl(fl(cn + ssq) - 2*dot), dot =
// k-ascending single-accumulator fma (BLAS microkernel order).
// ---------------------------------------------------------------------------
__global__ __launch_bounds__(256)
void vq_main(const float* __restrict__ z, const float* __restrict__ cb,
             float* __restrict__ out, float* __restrict__ partials)
{
    __shared__ __align__(16) float zsh[RPB * ED];     // 8 KB
    __shared__ __align__(16) float et[ED * CHUNK];    // 64 KB (transposed chunk)
    __shared__ __align__(16) float sq[CHUNK];         // 1 KB
    __shared__ int   idxsh[RPB];
    __shared__ float wsum[4];

    const int tid  = threadIdx.x;
    const int lane = tid & 63;
    const int w    = tid >> 6;                // wave 0..3
    const int rowbase = blockIdx.x * RPB;

    // ---- stage z (32 rows x 64 dims) ----
    {
        const f4* zg = (const f4*)(z + (size_t)rowbase * ED);
        f4* zs = (f4*)zsh;
        zs[tid]       = zg[tid];
        zs[tid + 256] = zg[tid + 256];
    }
    __syncthreads();

    // ---- row norms, numpy pairwise-8 replication ----
    float cn[RPW];
    {
        float rj;
        {
#pragma clang fp contract(off)
            const int rl = lane >> 3;          // row within wave's 8
            const int jj = lane & 7;           // accumulator index
            const float* zr = &zsh[(w * RPW + rl) * ED];
            float a = 0.f;
#pragma unroll
            for (int i = 0; i < 8; ++i) { float v = zr[8 * i + jj]; a += v * v; }
            rj = a;
        }
        // butterfly == ((r0+r1)+(r2+r3))+((r4+r5)+(r6+r7)) in every lane
        rj += __shfl_xor(rj, 1);
        rj += __shfl_xor(rj, 2);
        rj += __shfl_xor(rj, 4);
#pragma unroll
        for (int r = 0; r < RPW; ++r) cn[r] = __shfl(rj, r * 8);
    }

    float bestv[RPW];
    int   besti[RPW];
#pragma unroll
    for (int r = 0; r < RPW; ++r) { bestv[r] = INFINITY; besti[r] = 0; }

    const f4* zs4 = (const f4*)zsh;   // [32][16] f4
    const f4* et4 = (const f4*)et;    // [64][64] f4
    const f4* sq4 = (const f4*)sq;    // [64] f4

    for (int ch = 0; ch < 4; ++ch) {
        __syncthreads();   // previous chunk's readers done before overwrite
        // ---- stage codebook chunk: code = ch*256 + tid ----
        {
            const int code = ch * CHUNK + tid;
            const f4* crow = (const f4*)(cb + (size_t)code * ED);
            float v[ED];
#pragma unroll
            for (int i = 0; i < 16; ++i) {
                f4 t = crow[i];
                v[4 * i + 0] = t.x; v[4 * i + 1] = t.y;
                v[4 * i + 2] = t.z; v[4 * i + 3] = t.w;
            }
            {
#pragma clang fp contract(off)
                float r0 = v[0] * v[0], r1 = v[1] * v[1];
                float r2 = v[2] * v[2], r3 = v[3] * v[3];
                float r4 = v[4] * v[4], r5 = v[5] * v[5];
                float r6 = v[6] * v[6], r7 = v[7] * v[7];
#pragma unroll
                for (int i = 8; i < ED; i += 8) {
                    r0 += v[i + 0] * v[i + 0]; r1 += v[i + 1] * v[i + 1];
                    r2 += v[i + 2] * v[i + 2]; r3 += v[i + 3] * v[i + 3];
                    r4 += v[i + 4] * v[i + 4]; r5 += v[i + 5] * v[i + 5];
                    r6 += v[i + 6] * v[i + 6]; r7 += v[i + 7] * v[i + 7];
                }
                sq[tid] = ((r0 + r1) + (r2 + r3)) + ((r4 + r5) + (r6 + r7));
            }
#pragma unroll
            for (int i = 0; i < ED; ++i) et[i * CHUNK + tid] = v[i];
        }
        __syncthreads();

        // ---- 32 rows x 256 codes: each lane 4 codes (f4 column = lane) ----
        f4 sv = sq4[lane];
        float svq[4] = {sv.x, sv.y, sv.z, sv.w};

        float acc[RPW][4];
#pragma unroll
        for (int r = 0; r < RPW; ++r)
            acc[r][0] = acc[r][1] = acc[r][2] = acc[r][3] = 0.f;

#pragma unroll 2
        for (int k4 = 0; k4 < 16; ++k4) {
            f4 e0 = et4[(4 * k4 + 0) * 64 + lane];
            f4 e1 = et4[(4 * k4 + 1) * 64 + lane];
            f4 e2 = et4[(4 * k4 + 2) * 64 + lane];
            f4 e3 = et4[(4 * k4 + 3) * 64 + lane];
#pragma unroll
            for (int r = 0; r < RPW; ++r) {
                f4 zv = zs4[(w * RPW + r) * 16 + k4];
                acc[r][0] = fmaf(zv.x, e0.x, acc[r][0]);
                acc[r][1] = fmaf(zv.x, e0.y, acc[r][1]);
                acc[r][2] = fmaf(zv.x, e0.z, acc[r][2]);
                acc[r][3] = fmaf(zv.x, e0.w, acc[r][3]);
                acc[r][0] = fmaf(zv.y, e1.x, acc[r][0]);
                acc[r][1] = fmaf(zv.y, e1.y, acc[r][1]);
                acc[r][2] = fmaf(zv.y, e1.z, acc[r][2]);
                acc[r][3] = fmaf(zv.y, e1.w, acc[r][3]);
                acc[r][0] = fmaf(zv.z, e2.x, acc[r][0]);
                acc[r][1] = fmaf(zv.z, e2.y, acc[r][1]);
                acc[r][2] = fmaf(zv.z, e2.z, acc[r][2]);
                acc[r][3] = fmaf(zv.z, e2.w, acc[r][3]);
                acc[r][0] = fmaf(zv.w, e3.x, acc[r][0]);
                acc[r][1] = fmaf(zv.w, e3.y, acc[r][1]);
                acc[r][2] = fmaf(zv.w, e3.z, acc[r][2]);
                acc[r][3] = fmaf(zv.w, e3.w, acc[r][3]);
            }
        }

        {
#pragma clang fp contract(off)
#pragma unroll
            for (int r = 0; r < RPW; ++r) {
#pragma unroll
                for (int q = 0; q < 4; ++q) {
                    float t1 = cn[r] + svq[q];
                    float d  = t1 - 2.0f * acc[r][q];   // 2*acc exact
                    int j = ch * 256 + lane * 4 + q;
                    if (d < bestv[r]) { bestv[r] = d; besti[r] = j; }
                }
            }
        }
    }

    // ---- cross-lane lexicographic (val, idx) argmin + epilogue ----
    float lp = 0.f;
#pragma unroll
    for (int r = 0; r < RPW; ++r) {
        float v = bestv[r];
        int   i = besti[r];
#pragma unroll
        for (int m = 1; m < 64; m <<= 1) {
            float ov = __shfl_xor(v, m);
            int   oi = __shfl_xor(i, m);
            if (ov < v || (ov == v && oi < i)) { v = ov; i = oi; }
        }
        i &= (NE - 1);                      // defensive: no-op when correct
        const int grow = rowbase + w * RPW + r;
        float zq, zz, diff, st;
        {
#pragma clang fp contract(off)
            zq   = cb[(size_t)i * ED + lane];
            zz   = zsh[(w * RPW + r) * ED + lane];
            diff = zq - zz;                 // (z_q - z)
            st   = zz + diff;               // z + sg(z_q - z)
            lp  += diff * diff;
        }
        out[(size_t)grow * ED + lane] = st;            // f32 store
        if (lane == 0) idxsh[w * RPW + r] = i;
    }

    // ---- loss partial (deterministic) ----
#pragma unroll
    for (int m = 1; m < 64; m <<= 1) lp += __shfl_xor(lp, m);
    if (lane == 0) wsum[w] = lp;
    __syncthreads();

    // ---- uniform coalesced idx store (f32) ----
    if (tid < RPB) {
        int iv = idxsh[tid] & (NE - 1);
        out[(size_t)NROWS * ED + rowbase + tid] = (float)iv;
    }
    if (tid == 0)
        partials[blockIdx.x] = (wsum[0] + wsum[1]) + (wsum[2] + wsum[3]);
}

// ---------------------------------------------------------------------------
// Finalize: deterministic tree-sum of 1024 partials -> loss scalar (f32)
// ---------------------------------------------------------------------------
__global__ void vq_finalize(const float* __restrict__ partials,
                            float* __restrict__ out)
{
    __shared__ float red[256];
    int t = threadIdx.x;
    float s = (partials[t] + partials[t + 256]) + (partials[t + 512] + partials[t + 768]);
    red[t] = s;
    __syncthreads();
    for (int m = 128; m > 0; m >>= 1) {
        if (t < m) red[t] += red[t + m];
        __syncthreads();
    }
    if (t == 0) {
        float mean = red[0] / (float)((size_t)NROWS * ED);
        float loss = mean + 0.25f * mean;    // mean + BETA*mean (sg: same value)
        out[(size_t)NROWS * ED + NROWS] = loss;
    }
}

extern "C" void kernel_launch(void* const* d_in, const int* in_sizes, int n_in,
                              void* d_out, int out_size, void* d_ws, size_t ws_size,
                              hipStream_t stream)
{
    (void)in_sizes; (void)n_in; (void)out_size; (void)ws_size;
    const float* z  = (const float*)d_in[0];
    const float* cb = (const float*)d_in[1];
    float* out = (float*)d_out;              // f32 output buffer
    float* partials = (float*)d_ws;          // 1024 f32 = 4 KB only

    vq_main<<<1024, 256, 0, stream>>>(z, cb, out, partials);
    vq_finalize<<<1, 256, 0, stream>>>(partials, out);
}